// Round 4
// baseline (1219.481 us; speedup 1.0000x reference)
//
#include <hip/hip_runtime.h>

#define N_NODES 100000
#define N_EDGES 1600000
#define DIM 128
#define NGRAPH 64
#define M_PAD 100096   // 782 * 128
#define NBUCKET 782    // ceil(100000 / 128)
#define BCAP 4096      // max edges per bucket staged in LDS (mean 2046, sigma ~45)

typedef __attribute__((ext_vector_type(8))) short bf16x8;
typedef __attribute__((ext_vector_type(4))) float floatx4;

static __device__ __forceinline__ unsigned int f2bf(float f) {
    unsigned int u = __builtin_bit_cast(unsigned int, f);
    return (u + 0x7FFFu + ((u >> 16) & 1u)) >> 16;
}
static __device__ __forceinline__ float bf2f(unsigned short b) {
    unsigned int u = ((unsigned int)b) << 16;
    return __builtin_bit_cast(float, u);
}

// ---------------- dtype conversions ----------------

__global__ void k_x2bf(const float* __restrict__ x, unsigned short* __restrict__ xb) {
    size_t i = (size_t)(blockIdx.x * 256 + threadIdx.x) * 4;
    float4 v = *(const float4*)(x + i);
    uint2 o;
    o.x = f2bf(v.x) | (f2bf(v.y) << 16);
    o.y = f2bf(v.z) | (f2bf(v.w) << 16);
    *(uint2*)(xb + i) = o;
}

// Wt[n*256 + k] = (k<128 ? Wl[k][n] : Wr[k-128][n]) as bf16  (k-contiguous per col)
__global__ void k_wcvt(const float* __restrict__ Wl, const float* __restrict__ Wr,
                       unsigned short* __restrict__ Wt) {
    int id = blockIdx.x * 256 + threadIdx.x;  // 32768
    int n = id >> 8, k = id & 255;
    float v = (k < 128) ? Wl[k * 128 + n] : Wr[(k - 128) * 128 + n];
    Wt[n * 256 + k] = (unsigned short)f2bf(v);
}

// ---------------- bucketed CSR build ----------------

__global__ void k_bcount(const int* __restrict__ dst, int* __restrict__ bcnt) {
    int e = blockIdx.x * 256 + threadIdx.x;
    if (e < N_EDGES) atomicAdd(&bcnt[dst[e] >> 7], 1);
}

__global__ void k_bscan(const int* __restrict__ bcnt, int* __restrict__ bbase) {
    __shared__ int s[256];
    int tid = threadIdx.x;
    int v[4];
    int sum = 0;
#pragma unroll
    for (int j = 0; j < 4; j++) {
        int idx = tid * 4 + j;
        v[j] = (idx < NBUCKET) ? bcnt[idx] : 0;
        sum += v[j];
    }
    s[tid] = sum;
    __syncthreads();
    for (int off = 1; off < 256; off <<= 1) {
        int t = (tid >= off) ? s[tid - off] : 0;
        __syncthreads();
        s[tid] += t;
        __syncthreads();
    }
    int run = s[tid] - sum;  // exclusive prefix
#pragma unroll
    for (int j = 0; j < 4; j++) {
        int idx = tid * 4 + j;
        if (idx <= NBUCKET) bbase[idx] = run;
        run += v[j];
    }
}

// staging[pos] = src (17b) | dst_local (7b) << 25, bucket-partitioned
__global__ void k_scatter(const int* __restrict__ src, const int* __restrict__ dst,
                          const int* __restrict__ bbase, int* __restrict__ bcur,
                          unsigned int* __restrict__ staging) {
    int e = blockIdx.x * 256 + threadIdx.x;
    if (e >= N_EDGES) return;
    int d = dst[e];
    int b = d >> 7;
    int pos = bbase[b] + atomicAdd(&bcur[b], 1);
    staging[pos] = (unsigned int)src[e] | ((unsigned int)(d & 127) << 25);
}

// one block per bucket: LDS counting sort over 128 local nodes,
// emit rowptr for this node range and fully coalesced col.
__global__ __launch_bounds__(256) void k_bsort(const unsigned int* __restrict__ staging,
                                               const int* __restrict__ bbase,
                                               int* __restrict__ rowptr,
                                               int* __restrict__ col) {
    __shared__ unsigned int lpk[BCAP];
    __shared__ int lcol[BCAP];
    __shared__ int loff[129];
    __shared__ int lcur[128];
    int b = blockIdx.x, tid = threadIdx.x;
    int gbase = bbase[b];
    int nE = bbase[b + 1] - gbase;
    if (tid < 128) {
        loff[tid] = 0;
        lcur[tid] = 0;
    }
    __syncthreads();
    for (int i = tid; i < nE; i += 256) {
        unsigned int p = staging[gbase + i];
        if (i < BCAP) lpk[i] = p;
        atomicAdd(&loff[p >> 25], 1);
    }
    __syncthreads();
    // exclusive scan of 128 counts by wave 0
    if (tid < 64) {
        int c0 = loff[2 * tid], c1 = loff[2 * tid + 1];
        int ps = c0 + c1;
        for (int off = 1; off < 64; off <<= 1) {
            int t = __shfl_up(ps, off);
            if (tid >= off) ps += t;
        }
        int excl = ps - (c0 + c1);
        loff[2 * tid] = excl;
        loff[2 * tid + 1] = excl + c0;
        if (tid == 63) loff[128] = ps;
    }
    __syncthreads();
    if (tid < 128) {
        int idx = b * 128 + tid;
        if (idx < N_NODES) rowptr[idx] = gbase + loff[tid];
    }
    if (tid == 0 && b == NBUCKET - 1) rowptr[N_NODES] = N_EDGES;
    if (nE <= BCAP) {
        for (int i = tid; i < nE; i += 256) {
            unsigned int p = lpk[i];
            int d = p >> 25;
            int pos = loff[d] + atomicAdd(&lcur[d], 1);
            lcol[pos] = (int)(p & 0x1FFFFFFu);
        }
        __syncthreads();
        for (int i = tid; i < nE; i += 256) col[gbase + i] = lcol[i];
    } else {  // statistically impossible fallback, kept for safety
        for (int i = tid; i < nE; i += 256) {
            unsigned int p = staging[gbase + i];
            int d = p >> 25;
            int pos = loff[d] + atomicAdd(&lcur[d], 1);
            col[gbase + pos] = (int)(p & 0x1FFFFFFu);
        }
    }
}

// ---------------- mean aggregation, bf16 in/out ----------------
// one wave per node; quarter q handles neighbors start+q, start+q+4, ...
// lane t covers dims t*8..t*8+7 (16B loads); 4 rows in flight; fp32 acc.

__global__ __launch_bounds__(256) void k_gather_bf(
    const unsigned short* __restrict__ hin, const int* __restrict__ rowptr,
    const int* __restrict__ col, unsigned short* __restrict__ agg) {
    int lane = threadIdx.x & 63;
    int node = blockIdx.x * 4 + (threadIdx.x >> 6);
    int q = lane >> 4, t = lane & 15;
    int start = rowptr[node], end = rowptr[node + 1];
    float acc[8];
#pragma unroll
    for (int j = 0; j < 8; j++) acc[j] = 0.f;

    int c = start + q;
    while (c + 12 < end) {  // 4 rows in flight per lane
        int i0 = col[c], i1 = col[c + 4], i2 = col[c + 8], i3 = col[c + 12];
        uint4 v0 = *(const uint4*)(hin + (size_t)i0 * DIM + t * 8);
        uint4 v1 = *(const uint4*)(hin + (size_t)i1 * DIM + t * 8);
        uint4 v2 = *(const uint4*)(hin + (size_t)i2 * DIM + t * 8);
        uint4 v3 = *(const uint4*)(hin + (size_t)i3 * DIM + t * 8);
        const unsigned int* p0 = &v0.x;
        const unsigned int* p1 = &v1.x;
        const unsigned int* p2 = &v2.x;
        const unsigned int* p3 = &v3.x;
#pragma unroll
        for (int j = 0; j < 4; j++) {
            acc[2 * j + 0] += bf2f((unsigned short)(p0[j] & 0xFFFF)) +
                              bf2f((unsigned short)(p1[j] & 0xFFFF)) +
                              bf2f((unsigned short)(p2[j] & 0xFFFF)) +
                              bf2f((unsigned short)(p3[j] & 0xFFFF));
            acc[2 * j + 1] += bf2f((unsigned short)(p0[j] >> 16)) +
                              bf2f((unsigned short)(p1[j] >> 16)) +
                              bf2f((unsigned short)(p2[j] >> 16)) +
                              bf2f((unsigned short)(p3[j] >> 16));
        }
        c += 16;
    }
    while (c < end) {
        int i0 = col[c];
        uint4 v0 = *(const uint4*)(hin + (size_t)i0 * DIM + t * 8);
        const unsigned int* p0 = &v0.x;
#pragma unroll
        for (int j = 0; j < 4; j++) {
            acc[2 * j + 0] += bf2f((unsigned short)(p0[j] & 0xFFFF));
            acc[2 * j + 1] += bf2f((unsigned short)(p0[j] >> 16));
        }
        c += 4;
    }
#pragma unroll
    for (int j = 0; j < 8; j++) {
        acc[j] += __shfl_xor(acc[j], 16);
        acc[j] += __shfl_xor(acc[j], 32);
    }
    if (q == 0) {
        int deg = end - start;
        float scale = 1.f / (float)(deg > 0 ? deg : 1);
        uint4 o;
        unsigned int* po = &o.x;
#pragma unroll
        for (int j = 0; j < 4; j++)
            po[j] = f2bf(acc[2 * j] * scale) | (f2bf(acc[2 * j + 1] * scale) << 16);
        *(uint4*)(agg + (size_t)node * DIM + t * 8) = o;
    }
}

// ---------------- fused linear via MFMA ----------------

template <bool RELU>
__global__ __launch_bounds__(256) void k_linear_mfma(
    const unsigned short* __restrict__ aggb, const unsigned short* __restrict__ hb,
    const unsigned short* __restrict__ Wt, const float* __restrict__ bl,
    unsigned short* __restrict__ hout) {
    int tid = threadIdx.x;
    int w = tid >> 6, lane = tid & 63;
    int t = lane & 15, q = lane >> 4;
    size_t i0 = (size_t)blockIdx.x * 128;

    bf16x8 bfrag[2][8];
#pragma unroll
    for (int ct2 = 0; ct2 < 2; ct2++)
#pragma unroll
        for (int ks = 0; ks < 8; ks++)
            bfrag[ct2][ks] =
                *(const bf16x8*)(Wt + (size_t)(w * 32 + ct2 * 16 + t) * 256 + ks * 32 + q * 8);

    floatx4 acc[8][2];
#pragma unroll
    for (int rt = 0; rt < 8; rt++)
#pragma unroll
        for (int c = 0; c < 2; c++) acc[rt][c] = (floatx4){0.f, 0.f, 0.f, 0.f};

    bf16x8 a_cur[8];
#pragma unroll
    for (int rt = 0; rt < 8; rt++)
        a_cur[rt] = *(const bf16x8*)(aggb + (i0 + rt * 16 + t) * DIM + q * 8);

#pragma unroll
    for (int ks = 0; ks < 8; ks++) {
        bf16x8 a_nxt[8];
        if (ks < 7) {
            const unsigned short* base = ((ks + 1) < 4) ? aggb : hb;
            int ko = ((ks + 1) & 3) * 32;
#pragma unroll
            for (int rt = 0; rt < 8; rt++)
                a_nxt[rt] = *(const bf16x8*)(base + (i0 + rt * 16 + t) * DIM + ko + q * 8);
        }
#pragma unroll
        for (int rt = 0; rt < 8; rt++) {
            acc[rt][0] = __builtin_amdgcn_mfma_f32_16x16x32_bf16(a_cur[rt], bfrag[0][ks],
                                                                 acc[rt][0], 0, 0, 0);
            acc[rt][1] = __builtin_amdgcn_mfma_f32_16x16x32_bf16(a_cur[rt], bfrag[1][ks],
                                                                 acc[rt][1], 0, 0, 0);
        }
        if (ks < 7) {
#pragma unroll
            for (int rt = 0; rt < 8; rt++) a_cur[rt] = a_nxt[rt];
        }
    }

    float b0 = bl[w * 32 + t];
    float b1 = bl[w * 32 + 16 + t];
#pragma unroll
    for (int rt = 0; rt < 8; rt++) {
#pragma unroll
        for (int r = 0; r < 4; r++) {
            size_t row = i0 + rt * 16 + q * 4 + r;
            float v0 = acc[rt][0][r] + b0;
            float v1 = acc[rt][1][r] + b1;
            if (RELU) {
                v0 = fmaxf(v0, 0.f);
                v1 = fmaxf(v1, 0.f);
            }
            hout[row * DIM + w * 32 + t] = (unsigned short)f2bf(v0);
            hout[row * DIM + w * 32 + 16 + t] = (unsigned short)f2bf(v1);
        }
    }
}

// ---------------- per-graph mean pool (batch sorted), bf16 input ----------------

__global__ void k_pool(const unsigned short* __restrict__ h, const int* __restrict__ batch,
                       float* __restrict__ pooled, float* __restrict__ gcnt) {
    int tid = threadIdx.x;
    int d = tid & 127, half = tid >> 7;
    int n0 = blockIdx.x * 64 + half * 32;
    if (n0 >= N_NODES) return;
    int nend = n0 + 32;
    if (nend > N_NODES) nend = N_NODES;
    float acc = 0.f;
    int cur = batch[n0];
    int run = 0;
    for (int n = n0; n < nend; n++) {
        int g = batch[n];
        if (g != cur) {
            atomicAdd(&pooled[cur * DIM + d], acc);
            if (d == 0) atomicAdd(&gcnt[cur], (float)run);
            acc = 0.f; run = 0; cur = g;
        }
        acc += bf2f(h[(size_t)n * DIM + d]);
        run++;
    }
    atomicAdd(&pooled[cur * DIM + d], acc);
    if (d == 0) atomicAdd(&gcnt[cur], (float)run);
}

__global__ void k_final(const float* __restrict__ pooled, const float* __restrict__ gcnt,
                        const float* __restrict__ Wlin, const float* __restrict__ blin,
                        float* __restrict__ out) {
    int t = threadIdx.x;  // 128 threads
    int g = t >> 1, o = t & 1;
    float sum = 0.f;
#pragma unroll 8
    for (int k = 0; k < DIM; k++) sum += pooled[g * DIM + k] * Wlin[k * 2 + o];
    float c = gcnt[g];
    out[g * 2 + o] = sum / fmaxf(c, 1.f) + blin[o];
}

// ---------------- launch ----------------

static inline size_t align_up(size_t v, size_t a) { return (v + a - 1) & ~(a - 1); }

extern "C" void kernel_launch(void* const* d_in, const int* in_sizes, int n_in,
                              void* d_out, int out_size, void* d_ws, size_t ws_size,
                              hipStream_t stream) {
    const float* x     = (const float*)d_in[0];
    const int*   ei    = (const int*)d_in[1];
    const int*   src   = ei;
    const int*   dst   = ei + N_EDGES;
    const int*   batch = (const int*)d_in[2];
    const float* Wl1 = (const float*)d_in[3];
    const float* bl1 = (const float*)d_in[4];
    const float* Wr1 = (const float*)d_in[5];
    const float* Wl2 = (const float*)d_in[6];
    const float* bl2 = (const float*)d_in[7];
    const float* Wr2 = (const float*)d_in[8];
    const float* Wl3 = (const float*)d_in[9];
    const float* bl3 = (const float*)d_in[10];
    const float* Wr3 = (const float*)d_in[11];
    const float* Wlin = (const float*)d_in[12];
    const float* blin = (const float*)d_in[13];
    float* out = (float*)d_out;

    char* p = (char*)d_ws;
    size_t off = 0;
    auto carve = [&](size_t bytes) -> void* {
        void* r = p + off;
        off = align_up(off + bytes, 256);
        return r;
    };
    int* rowptr = (int*)carve((N_NODES + 1) * sizeof(int));
    // bcnt and bcur MUST be one contiguous carve so a single memset covers both
    // (separate 256B-aligned carves left the tail of bcur 0xAA-poisoned -> OOB crash)
    int* bcnt   = (int*)carve(2 * NBUCKET * sizeof(int));
    int* bcur   = bcnt + NBUCKET;
    int* bbase  = (int*)carve((NBUCKET + 1) * sizeof(int));
    int* col    = (int*)carve((size_t)N_EDGES * sizeof(int));
    unsigned short* bufA = (unsigned short*)carve((size_t)M_PAD * DIM * 2);
    unsigned short* bufB = (unsigned short*)carve((size_t)M_PAD * DIM * 2);
    unsigned short* bufC = (unsigned short*)carve((size_t)M_PAD * DIM * 2);
    unsigned short* agg  = (unsigned short*)carve((size_t)M_PAD * DIM * 2);
    unsigned short* Wt1  = (unsigned short*)carve(256 * 128 * 2);
    unsigned short* Wt2  = (unsigned short*)carve(256 * 128 * 2);
    unsigned short* Wt3  = (unsigned short*)carve(256 * 128 * 2);
    float* pooled = (float*)carve((size_t)NGRAPH * DIM * sizeof(float));
    float* gcnt   = (float*)carve((size_t)NGRAPH * sizeof(float));
    // staging is dead after k_bsort; bufB is first written in layer 1's linear
    // (later on the same stream) -> safe alias, saves 6.4 MB of workspace.
    unsigned int* staging = (unsigned int*)bufB;

    // ---- CSR build (bucketed counting sort) ----
    hipMemsetAsync(bcnt, 0, 2 * NBUCKET * sizeof(int), stream);
    k_bcount<<<N_EDGES / 256, 256, 0, stream>>>(dst, bcnt);
    k_bscan<<<1, 256, 0, stream>>>(bcnt, bbase);
    k_scatter<<<N_EDGES / 256, 256, 0, stream>>>(src, dst, bbase, bcur, staging);
    k_bsort<<<NBUCKET, 256, 0, stream>>>(staging, bbase, rowptr, col);

    // ---- conversions ----
    k_x2bf<<<N_NODES * DIM / 4 / 256, 256, 0, stream>>>(x, bufA);
    k_wcvt<<<128, 256, 0, stream>>>(Wl1, Wr1, Wt1);
    k_wcvt<<<128, 256, 0, stream>>>(Wl2, Wr2, Wt2);
    k_wcvt<<<128, 256, 0, stream>>>(Wl3, Wr3, Wt3);

    const int GRID_G = N_NODES / 4;        // 25000
    const int GRID_L = M_PAD / 128;        // 782

    // ---- layer 1 ----
    k_gather_bf<<<GRID_G, 256, 0, stream>>>(bufA, rowptr, col, agg);
    k_linear_mfma<true><<<GRID_L, 256, 0, stream>>>(agg, bufA, Wt1, bl1, bufB);
    // ---- layer 2 ----
    k_gather_bf<<<GRID_G, 256, 0, stream>>>(bufB, rowptr, col, agg);
    k_linear_mfma<true><<<GRID_L, 256, 0, stream>>>(agg, bufB, Wt2, bl2, bufC);
    // ---- layer 3 ----
    k_gather_bf<<<GRID_G, 256, 0, stream>>>(bufC, rowptr, col, agg);
    k_linear_mfma<false><<<GRID_L, 256, 0, stream>>>(agg, bufC, Wt3, bl3, bufA);

    // ---- pool + final ----
    hipMemsetAsync(pooled, 0, NGRAPH * DIM * sizeof(float) + NGRAPH * sizeof(float), stream);
    k_pool<<<(N_NODES + 63) / 64, 256, 0, stream>>>(bufA, batch, pooled, gcnt);
    k_final<<<1, 128, 0, stream>>>(pooled, gcnt, Wlin, blin, out);
}

// Round 5
// 490.885 us; speedup vs baseline: 2.4843x; 2.4843x over previous
//
#include <hip/hip_runtime.h>

#define N_NODES 100000
#define N_EDGES 1600000
#define DIM 128
#define NGRAPH 64
#define M_PAD 100096   // 782 * 128
#define NBUCKET 782    // ceil(100000 / 128)
#define BCAP 4096      // staging capacity per bucket (mean 2046, sigma ~45)
#define CHUNK 8192     // edges per scatter block

typedef __attribute__((ext_vector_type(8))) short bf16x8;
typedef __attribute__((ext_vector_type(4))) float floatx4;

static __device__ __forceinline__ unsigned int f2bf(float f) {
    unsigned int u = __builtin_bit_cast(unsigned int, f);
    return (u + 0x7FFFu + ((u >> 16) & 1u)) >> 16;
}
static __device__ __forceinline__ float bf2f(unsigned short b) {
    unsigned int u = ((unsigned int)b) << 16;
    return __builtin_bit_cast(float, u);
}

// ---------------- dtype conversions ----------------

__global__ void k_x2bf(const float* __restrict__ x, unsigned short* __restrict__ xb) {
    size_t i = (size_t)(blockIdx.x * 256 + threadIdx.x) * 4;
    float4 v = *(const float4*)(x + i);
    uint2 o;
    o.x = f2bf(v.x) | (f2bf(v.y) << 16);
    o.y = f2bf(v.z) | (f2bf(v.w) << 16);
    *(uint2*)(xb + i) = o;
}

// Wt[n*256 + k] = (k<128 ? Wl[k][n] : Wr[k-128][n]) as bf16  (k-contiguous per col)
__global__ void k_wcvt(const float* __restrict__ Wl, const float* __restrict__ Wr,
                       unsigned short* __restrict__ Wt) {
    int id = blockIdx.x * 256 + threadIdx.x;  // 32768
    int n = id >> 8, k = id & 255;
    float v = (k < 128) ? Wl[k * 128 + n] : Wr[(k - 128) * 128 + n];
    Wt[n * 256 + k] = (unsigned short)f2bf(v);
}

// ---------------- bucketed CSR build ----------------
// k_scatter2: per-block LDS histogram over 782 buckets, ONE global atomic per
// (bucket, block) to reserve a contiguous run, then write edges into the
// bucket's fixed-capacity staging region. Replaces k_bcount + old k_scatter
// (3.2M 2046-deep global atomic chains -> 153K 196-deep).

__global__ __launch_bounds__(1024) void k_scatter2(const int* __restrict__ src,
                                                   const int* __restrict__ dst,
                                                   int* __restrict__ bcur,
                                                   unsigned int* __restrict__ staging) {
    __shared__ int cnt[NBUCKET];
    __shared__ int gbase[NBUCKET];
    __shared__ int pos[NBUCKET];
    int tid = threadIdx.x;
    int e0 = blockIdx.x * CHUNK;
    for (int i = tid; i < NBUCKET; i += 1024) {
        cnt[i] = 0;
        pos[i] = 0;
    }
    __syncthreads();
    int s[8], d[8];
#pragma unroll
    for (int j = 0; j < 8; j++) {
        int e = e0 + j * 1024 + tid;
        if (e < N_EDGES) {
            s[j] = src[e];
            d[j] = dst[e];
            atomicAdd(&cnt[d[j] >> 7], 1);
        } else {
            d[j] = -1;
        }
    }
    __syncthreads();
    for (int i = tid; i < NBUCKET; i += 1024) {
        int c = cnt[i];
        if (c > 0) gbase[i] = atomicAdd(&bcur[i], c);
    }
    __syncthreads();
#pragma unroll
    for (int j = 0; j < 8; j++) {
        if (d[j] >= 0) {
            int b = d[j] >> 7;
            int gp = gbase[b] + atomicAdd(&pos[b], 1);
            if (gp < BCAP)  // 45-sigma guard: drop instead of corrupting
                staging[(size_t)b * BCAP + gp] =
                    (unsigned int)s[j] | ((unsigned int)(d[j] & 127) << 25);
        }
    }
}

// exclusive scan of the 782 per-bucket counts -> global col-array bases
__global__ void k_bscan(const int* __restrict__ bcnt, int* __restrict__ bbase) {
    __shared__ int s[256];
    int tid = threadIdx.x;
    int v[4];
    int sum = 0;
#pragma unroll
    for (int j = 0; j < 4; j++) {
        int idx = tid * 4 + j;
        v[j] = (idx < NBUCKET) ? bcnt[idx] : 0;
        sum += v[j];
    }
    s[tid] = sum;
    __syncthreads();
    for (int off = 1; off < 256; off <<= 1) {
        int t = (tid >= off) ? s[tid - off] : 0;
        __syncthreads();
        s[tid] += t;
        __syncthreads();
    }
    int run = s[tid] - sum;  // exclusive prefix
#pragma unroll
    for (int j = 0; j < 4; j++) {
        int idx = tid * 4 + j;
        if (idx <= NBUCKET) bbase[idx] = run;
        run += v[j];
    }
}

// one block per bucket: LDS counting sort over 128 local nodes,
// emit rowptr for this node range and fully coalesced col.
__global__ __launch_bounds__(256) void k_bsort(const unsigned int* __restrict__ staging,
                                               const int* __restrict__ bbase,
                                               int* __restrict__ rowptr,
                                               int* __restrict__ col) {
    __shared__ unsigned int lpk[BCAP];
    __shared__ int lcol[BCAP];
    __shared__ int loff[129];
    __shared__ int lcur[128];
    int b = blockIdx.x, tid = threadIdx.x;
    int gbase = bbase[b];
    int nE = bbase[b + 1] - gbase;
    if (nE > BCAP) nE = BCAP;
    if (tid < 128) {
        loff[tid] = 0;
        lcur[tid] = 0;
    }
    __syncthreads();
    const unsigned int* sb = staging + (size_t)b * BCAP;
    for (int i = tid; i < nE; i += 256) {
        unsigned int p = sb[i];
        lpk[i] = p;
        atomicAdd(&loff[p >> 25], 1);
    }
    __syncthreads();
    // exclusive scan of 128 counts by wave 0
    if (tid < 64) {
        int c0 = loff[2 * tid], c1 = loff[2 * tid + 1];
        int ps = c0 + c1;
        for (int off = 1; off < 64; off <<= 1) {
            int t = __shfl_up(ps, off);
            if (tid >= off) ps += t;
        }
        int excl = ps - (c0 + c1);
        loff[2 * tid] = excl;
        loff[2 * tid + 1] = excl + c0;
        if (tid == 63) loff[128] = ps;
    }
    __syncthreads();
    if (tid < 128) {
        int idx = b * 128 + tid;
        if (idx < N_NODES) rowptr[idx] = gbase + loff[tid];
    }
    if (tid == 0 && b == NBUCKET - 1) rowptr[N_NODES] = N_EDGES;
    for (int i = tid; i < nE; i += 256) {
        unsigned int p = lpk[i];
        int d = p >> 25;
        int pos = loff[d] + atomicAdd(&lcur[d], 1);
        lcol[pos] = (int)(p & 0x1FFFFFFu);
    }
    __syncthreads();
    for (int i = tid; i < nE; i += 256) col[gbase + i] = lcol[i];
}

// ---------------- mean aggregation, bf16 in/out ----------------
// one wave per node; quarter q handles neighbors start+q, start+q+4, ...
// lane t covers dims t*8..t*8+7 (16B loads); 4 rows in flight; fp32 acc.

__global__ __launch_bounds__(256) void k_gather_bf(
    const unsigned short* __restrict__ hin, const int* __restrict__ rowptr,
    const int* __restrict__ col, unsigned short* __restrict__ agg) {
    int lane = threadIdx.x & 63;
    int node = blockIdx.x * 4 + (threadIdx.x >> 6);
    int q = lane >> 4, t = lane & 15;
    int start = rowptr[node], end = rowptr[node + 1];
    float acc[8];
#pragma unroll
    for (int j = 0; j < 8; j++) acc[j] = 0.f;

    int c = start + q;
    while (c + 12 < end) {  // 4 rows in flight per lane
        int i0 = col[c], i1 = col[c + 4], i2 = col[c + 8], i3 = col[c + 12];
        uint4 v0 = *(const uint4*)(hin + (size_t)i0 * DIM + t * 8);
        uint4 v1 = *(const uint4*)(hin + (size_t)i1 * DIM + t * 8);
        uint4 v2 = *(const uint4*)(hin + (size_t)i2 * DIM + t * 8);
        uint4 v3 = *(const uint4*)(hin + (size_t)i3 * DIM + t * 8);
        const unsigned int* p0 = &v0.x;
        const unsigned int* p1 = &v1.x;
        const unsigned int* p2 = &v2.x;
        const unsigned int* p3 = &v3.x;
#pragma unroll
        for (int j = 0; j < 4; j++) {
            acc[2 * j + 0] += bf2f((unsigned short)(p0[j] & 0xFFFF)) +
                              bf2f((unsigned short)(p1[j] & 0xFFFF)) +
                              bf2f((unsigned short)(p2[j] & 0xFFFF)) +
                              bf2f((unsigned short)(p3[j] & 0xFFFF));
            acc[2 * j + 1] += bf2f((unsigned short)(p0[j] >> 16)) +
                              bf2f((unsigned short)(p1[j] >> 16)) +
                              bf2f((unsigned short)(p2[j] >> 16)) +
                              bf2f((unsigned short)(p3[j] >> 16));
        }
        c += 16;
    }
    while (c < end) {
        int i0 = col[c];
        uint4 v0 = *(const uint4*)(hin + (size_t)i0 * DIM + t * 8);
        const unsigned int* p0 = &v0.x;
#pragma unroll
        for (int j = 0; j < 4; j++) {
            acc[2 * j + 0] += bf2f((unsigned short)(p0[j] & 0xFFFF));
            acc[2 * j + 1] += bf2f((unsigned short)(p0[j] >> 16));
        }
        c += 4;
    }
#pragma unroll
    for (int j = 0; j < 8; j++) {
        acc[j] += __shfl_xor(acc[j], 16);
        acc[j] += __shfl_xor(acc[j], 32);
    }
    if (q == 0) {
        int deg = end - start;
        float scale = 1.f / (float)(deg > 0 ? deg : 1);
        uint4 o;
        unsigned int* po = &o.x;
#pragma unroll
        for (int j = 0; j < 4; j++)
            po[j] = f2bf(acc[2 * j] * scale) | (f2bf(acc[2 * j + 1] * scale) << 16);
        *(uint4*)(agg + (size_t)node * DIM + t * 8) = o;
    }
}

// ---------------- fused linear via MFMA ----------------

template <bool RELU>
__global__ __launch_bounds__(256) void k_linear_mfma(
    const unsigned short* __restrict__ aggb, const unsigned short* __restrict__ hb,
    const unsigned short* __restrict__ Wt, const float* __restrict__ bl,
    unsigned short* __restrict__ hout) {
    int tid = threadIdx.x;
    int w = tid >> 6, lane = tid & 63;
    int t = lane & 15, q = lane >> 4;
    size_t i0 = (size_t)blockIdx.x * 128;

    bf16x8 bfrag[2][8];
#pragma unroll
    for (int ct2 = 0; ct2 < 2; ct2++)
#pragma unroll
        for (int ks = 0; ks < 8; ks++)
            bfrag[ct2][ks] =
                *(const bf16x8*)(Wt + (size_t)(w * 32 + ct2 * 16 + t) * 256 + ks * 32 + q * 8);

    floatx4 acc[8][2];
#pragma unroll
    for (int rt = 0; rt < 8; rt++)
#pragma unroll
        for (int c = 0; c < 2; c++) acc[rt][c] = (floatx4){0.f, 0.f, 0.f, 0.f};

    bf16x8 a_cur[8];
#pragma unroll
    for (int rt = 0; rt < 8; rt++)
        a_cur[rt] = *(const bf16x8*)(aggb + (i0 + rt * 16 + t) * DIM + q * 8);

#pragma unroll
    for (int ks = 0; ks < 8; ks++) {
        bf16x8 a_nxt[8];
        if (ks < 7) {
            const unsigned short* base = ((ks + 1) < 4) ? aggb : hb;
            int ko = ((ks + 1) & 3) * 32;
#pragma unroll
            for (int rt = 0; rt < 8; rt++)
                a_nxt[rt] = *(const bf16x8*)(base + (i0 + rt * 16 + t) * DIM + ko + q * 8);
        }
#pragma unroll
        for (int rt = 0; rt < 8; rt++) {
            acc[rt][0] = __builtin_amdgcn_mfma_f32_16x16x32_bf16(a_cur[rt], bfrag[0][ks],
                                                                 acc[rt][0], 0, 0, 0);
            acc[rt][1] = __builtin_amdgcn_mfma_f32_16x16x32_bf16(a_cur[rt], bfrag[1][ks],
                                                                 acc[rt][1], 0, 0, 0);
        }
        if (ks < 7) {
#pragma unroll
            for (int rt = 0; rt < 8; rt++) a_cur[rt] = a_nxt[rt];
        }
    }

    float b0 = bl[w * 32 + t];
    float b1 = bl[w * 32 + 16 + t];
#pragma unroll
    for (int rt = 0; rt < 8; rt++) {
#pragma unroll
        for (int r = 0; r < 4; r++) {
            size_t row = i0 + rt * 16 + q * 4 + r;
            float v0 = acc[rt][0][r] + b0;
            float v1 = acc[rt][1][r] + b1;
            if (RELU) {
                v0 = fmaxf(v0, 0.f);
                v1 = fmaxf(v1, 0.f);
            }
            hout[row * DIM + w * 32 + t] = (unsigned short)f2bf(v0);
            hout[row * DIM + w * 32 + 16 + t] = (unsigned short)f2bf(v1);
        }
    }
}

// ---------------- per-graph mean pool (batch sorted), bf16 input ----------------

__global__ void k_pool(const unsigned short* __restrict__ h, const int* __restrict__ batch,
                       float* __restrict__ pooled, float* __restrict__ gcnt) {
    int tid = threadIdx.x;
    int d = tid & 127, half = tid >> 7;
    int n0 = blockIdx.x * 64 + half * 32;
    if (n0 >= N_NODES) return;
    int nend = n0 + 32;
    if (nend > N_NODES) nend = N_NODES;
    float acc = 0.f;
    int cur = batch[n0];
    int run = 0;
    for (int n = n0; n < nend; n++) {
        int g = batch[n];
        if (g != cur) {
            atomicAdd(&pooled[cur * DIM + d], acc);
            if (d == 0) atomicAdd(&gcnt[cur], (float)run);
            acc = 0.f; run = 0; cur = g;
        }
        acc += bf2f(h[(size_t)n * DIM + d]);
        run++;
    }
    atomicAdd(&pooled[cur * DIM + d], acc);
    if (d == 0) atomicAdd(&gcnt[cur], (float)run);
}

__global__ void k_final(const float* __restrict__ pooled, const float* __restrict__ gcnt,
                        const float* __restrict__ Wlin, const float* __restrict__ blin,
                        float* __restrict__ out) {
    int t = threadIdx.x;  // 128 threads
    int g = t >> 1, o = t & 1;
    float sum = 0.f;
#pragma unroll 8
    for (int k = 0; k < DIM; k++) sum += pooled[g * DIM + k] * Wlin[k * 2 + o];
    float c = gcnt[g];
    out[g * 2 + o] = sum / fmaxf(c, 1.f) + blin[o];
}

// ---------------- launch ----------------

static inline size_t align_up(size_t v, size_t a) { return (v + a - 1) & ~(a - 1); }

extern "C" void kernel_launch(void* const* d_in, const int* in_sizes, int n_in,
                              void* d_out, int out_size, void* d_ws, size_t ws_size,
                              hipStream_t stream) {
    const float* x     = (const float*)d_in[0];
    const int*   ei    = (const int*)d_in[1];
    const int*   src   = ei;
    const int*   dst   = ei + N_EDGES;
    const int*   batch = (const int*)d_in[2];
    const float* Wl1 = (const float*)d_in[3];
    const float* bl1 = (const float*)d_in[4];
    const float* Wr1 = (const float*)d_in[5];
    const float* Wl2 = (const float*)d_in[6];
    const float* bl2 = (const float*)d_in[7];
    const float* Wr2 = (const float*)d_in[8];
    const float* Wl3 = (const float*)d_in[9];
    const float* bl3 = (const float*)d_in[10];
    const float* Wr3 = (const float*)d_in[11];
    const float* Wlin = (const float*)d_in[12];
    const float* blin = (const float*)d_in[13];
    float* out = (float*)d_out;

    char* p = (char*)d_ws;
    size_t off = 0;
    auto carve = [&](size_t bytes) -> void* {
        void* r = p + off;
        off = align_up(off + bytes, 256);
        return r;
    };
    int* rowptr = (int*)carve((N_NODES + 1) * sizeof(int));
    int* bcur   = (int*)carve(NBUCKET * sizeof(int));
    int* bbase  = (int*)carve((NBUCKET + 1) * sizeof(int));
    int* col    = (int*)carve((size_t)N_EDGES * sizeof(int));
    unsigned short* bufA = (unsigned short*)carve((size_t)M_PAD * DIM * 2);
    unsigned short* bufB = (unsigned short*)carve((size_t)M_PAD * DIM * 2);
    unsigned short* bufC = (unsigned short*)carve((size_t)M_PAD * DIM * 2);
    unsigned short* agg  = (unsigned short*)carve((size_t)M_PAD * DIM * 2);
    unsigned short* Wt1  = (unsigned short*)carve(256 * 128 * 2);
    unsigned short* Wt2  = (unsigned short*)carve(256 * 128 * 2);
    unsigned short* Wt3  = (unsigned short*)carve(256 * 128 * 2);
    float* pooled = (float*)carve((size_t)NGRAPH * DIM * sizeof(float));
    float* gcnt   = (float*)carve((size_t)NGRAPH * sizeof(float));
    // staging (782*4096*4B = 12.8 MB) aliases bufB: dead after k_bsort, and
    // bufB is first written by layer-1's linear later on the same stream.
    unsigned int* staging = (unsigned int*)bufB;

    // ---- CSR build (chunk-reserved bucket scatter + per-bucket sort) ----
    hipMemsetAsync(bcur, 0, NBUCKET * sizeof(int), stream);
    k_scatter2<<<(N_EDGES + CHUNK - 1) / CHUNK, 1024, 0, stream>>>(src, dst, bcur, staging);
    k_bscan<<<1, 256, 0, stream>>>(bcur, bbase);
    k_bsort<<<NBUCKET, 256, 0, stream>>>(staging, bbase, rowptr, col);

    // ---- conversions ----
    k_x2bf<<<N_NODES * DIM / 4 / 256, 256, 0, stream>>>(x, bufA);
    k_wcvt<<<128, 256, 0, stream>>>(Wl1, Wr1, Wt1);
    k_wcvt<<<128, 256, 0, stream>>>(Wl2, Wr2, Wt2);
    k_wcvt<<<128, 256, 0, stream>>>(Wl3, Wr3, Wt3);

    const int GRID_G = N_NODES / 4;        // 25000
    const int GRID_L = M_PAD / 128;        // 782

    // ---- layer 1 ----
    k_gather_bf<<<GRID_G, 256, 0, stream>>>(bufA, rowptr, col, agg);
    k_linear_mfma<true><<<GRID_L, 256, 0, stream>>>(agg, bufA, Wt1, bl1, bufB);
    // ---- layer 2 ----
    k_gather_bf<<<GRID_G, 256, 0, stream>>>(bufB, rowptr, col, agg);
    k_linear_mfma<true><<<GRID_L, 256, 0, stream>>>(agg, bufB, Wt2, bl2, bufC);
    // ---- layer 3 ----
    k_gather_bf<<<GRID_G, 256, 0, stream>>>(bufC, rowptr, col, agg);
    k_linear_mfma<false><<<GRID_L, 256, 0, stream>>>(agg, bufC, Wt3, bl3, bufA);

    // ---- pool + final ----
    hipMemsetAsync(pooled, 0, NGRAPH * DIM * sizeof(float) + NGRAPH * sizeof(float), stream);
    k_pool<<<(N_NODES + 63) / 64, 256, 0, stream>>>(bufA, batch, pooled, gcnt);
    k_final<<<1, 128, 0, stream>>>(pooled, gcnt, Wlin, blin, out);
}

// Round 7
// 486.236 us; speedup vs baseline: 2.5080x; 1.0096x over previous
//
#include <hip/hip_runtime.h>

#define N_NODES 100000
#define N_EDGES 1600000
#define DIM 128
#define NGRAPH 64
#define M_PAD 100096   // 782 * 128
#define NBUCKET 782    // ceil(100000 / 128)
#define BCAP 4096      // staging capacity per bucket (mean 2046, sigma ~45)
#define CHUNK 8192     // edges per scatter block
#define GBLOCKS 2048   // persistent gather blocks (8192 waves)
#define XBLOCKS 12500  // N_NODES*DIM/4/256 — x2bf conversion blocks

typedef __attribute__((ext_vector_type(8))) short bf16x8;
typedef __attribute__((ext_vector_type(4))) float floatx4;

static __device__ __forceinline__ unsigned int f2bf(float f) {
    unsigned int u = __builtin_bit_cast(unsigned int, f);
    return (u + 0x7FFFu + ((u >> 16) & 1u)) >> 16;
}
static __device__ __forceinline__ float bf2f(unsigned short b) {
    unsigned int u = ((unsigned int)b) << 16;
    return __builtin_bit_cast(float, u);
}

// ---------------- fused conversions: x -> bf16, 3x W -> transposed bf16 ----------------
// blocks [0, XBLOCKS): x2bf.  blocks [XBLOCKS, XBLOCKS+384): wcvt layers 0..2.

__global__ void k_convert(const float* __restrict__ x, unsigned short* __restrict__ xb,
                          const float* __restrict__ Wl1, const float* __restrict__ Wr1,
                          unsigned short* __restrict__ Wt1,
                          const float* __restrict__ Wl2, const float* __restrict__ Wr2,
                          unsigned short* __restrict__ Wt2,
                          const float* __restrict__ Wl3, const float* __restrict__ Wr3,
                          unsigned short* __restrict__ Wt3) {
    int b = blockIdx.x;
    if (b < XBLOCKS) {
        size_t i = (size_t)(b * 256 + threadIdx.x) * 4;
        float4 v = *(const float4*)(x + i);
        uint2 o;
        o.x = f2bf(v.x) | (f2bf(v.y) << 16);
        o.y = f2bf(v.z) | (f2bf(v.w) << 16);
        *(uint2*)(xb + i) = o;
    } else {
        int layer = (b - XBLOCKS) >> 7;
        const float* Wl = layer == 0 ? Wl1 : (layer == 1 ? Wl2 : Wl3);
        const float* Wr = layer == 0 ? Wr1 : (layer == 1 ? Wr2 : Wr3);
        unsigned short* Wt = layer == 0 ? Wt1 : (layer == 1 ? Wt2 : Wt3);
        int id = ((b - XBLOCKS) & 127) * 256 + threadIdx.x;  // 0..32767
        int n = id >> 8, k = id & 255;
        float v = (k < 128) ? Wl[k * 128 + n] : Wr[(k - 128) * 128 + n];
        Wt[n * 256 + k] = (unsigned short)f2bf(v);
    }
}

// ---------------- bucketed CSR build ----------------
// k_scatter2: per-block LDS histogram over 782 buckets, ONE global atomic per
// (bucket, block) to reserve a contiguous run, then write edges into the
// bucket's fixed-capacity staging region.

__global__ __launch_bounds__(1024) void k_scatter2(const int* __restrict__ src,
                                                   const int* __restrict__ dst,
                                                   int* __restrict__ bcur,
                                                   unsigned int* __restrict__ staging) {
    __shared__ int cnt[NBUCKET];
    __shared__ int gbase[NBUCKET];
    __shared__ int pos[NBUCKET];
    int tid = threadIdx.x;
    int e0 = blockIdx.x * CHUNK;
    for (int i = tid; i < NBUCKET; i += 1024) {
        cnt[i] = 0;
        pos[i] = 0;
    }
    __syncthreads();
    int s[8], d[8];
#pragma unroll
    for (int j = 0; j < 8; j++) {
        int e = e0 + j * 1024 + tid;
        if (e < N_EDGES) {
            s[j] = src[e];
            d[j] = dst[e];
            atomicAdd(&cnt[d[j] >> 7], 1);
        } else {
            d[j] = -1;
        }
    }
    __syncthreads();
    for (int i = tid; i < NBUCKET; i += 1024) {
        int c = cnt[i];
        if (c > 0) gbase[i] = atomicAdd(&bcur[i], c);
    }
    __syncthreads();
#pragma unroll
    for (int j = 0; j < 8; j++) {
        if (d[j] >= 0) {
            int b = d[j] >> 7;
            int gp = gbase[b] + atomicAdd(&pos[b], 1);
            if (gp < BCAP)  // 45-sigma guard: drop instead of corrupting
                staging[(size_t)b * BCAP + gp] =
                    (unsigned int)s[j] | ((unsigned int)(d[j] & 127) << 25);
        }
    }
}

// exclusive scan of the 782 per-bucket counts -> global col-array bases
__global__ void k_bscan(const int* __restrict__ bcnt, int* __restrict__ bbase) {
    __shared__ int s[256];
    int tid = threadIdx.x;
    int v[4];
    int sum = 0;
#pragma unroll
    for (int j = 0; j < 4; j++) {
        int idx = tid * 4 + j;
        v[j] = (idx < NBUCKET) ? bcnt[idx] : 0;
        sum += v[j];
    }
    s[tid] = sum;
    __syncthreads();
    for (int off = 1; off < 256; off <<= 1) {
        int t = (tid >= off) ? s[tid - off] : 0;
        __syncthreads();
        s[tid] += t;
        __syncthreads();
    }
    int run = s[tid] - sum;  // exclusive prefix
#pragma unroll
    for (int j = 0; j < 4; j++) {
        int idx = tid * 4 + j;
        if (idx <= NBUCKET) bbase[idx] = run;
        run += v[j];
    }
}

// one block per bucket: LDS counting sort over 128 local nodes,
// emit rowptr for this node range and fully coalesced col.
__global__ __launch_bounds__(256) void k_bsort(const unsigned int* __restrict__ staging,
                                               const int* __restrict__ bbase,
                                               int* __restrict__ rowptr,
                                               int* __restrict__ col) {
    __shared__ unsigned int lpk[BCAP];
    __shared__ int lcol[BCAP];
    __shared__ int loff[129];
    __shared__ int lcur[128];
    int b = blockIdx.x, tid = threadIdx.x;
    int gbase = bbase[b];
    int nE = bbase[b + 1] - gbase;
    if (nE > BCAP) nE = BCAP;
    if (tid < 128) {
        loff[tid] = 0;
        lcur[tid] = 0;
    }
    __syncthreads();
    const unsigned int* sb = staging + (size_t)b * BCAP;
    for (int i = tid; i < nE; i += 256) {
        unsigned int p = sb[i];
        lpk[i] = p;
        atomicAdd(&loff[p >> 25], 1);
    }
    __syncthreads();
    // exclusive scan of 128 counts by wave 0
    if (tid < 64) {
        int c0 = loff[2 * tid], c1 = loff[2 * tid + 1];
        int ps = c0 + c1;
        for (int off = 1; off < 64; off <<= 1) {
            int t = __shfl_up(ps, off);
            if (tid >= off) ps += t;
        }
        int excl = ps - (c0 + c1);
        loff[2 * tid] = excl;
        loff[2 * tid + 1] = excl + c0;
        if (tid == 63) loff[128] = ps;
    }
    __syncthreads();
    if (tid < 128) {
        int idx = b * 128 + tid;
        if (idx < N_NODES) rowptr[idx] = gbase + loff[tid];
    }
    if (tid == 0 && b == NBUCKET - 1) rowptr[N_NODES] = N_EDGES;
    for (int i = tid; i < nE; i += 256) {
        unsigned int p = lpk[i];
        int d = p >> 25;
        int pos = loff[d] + atomicAdd(&lcur[d], 1);
        lcol[pos] = (int)(p & 0x1FFFFFFu);
    }
    __syncthreads();
    for (int i = tid; i < nE; i += 256) col[gbase + i] = lcol[i];
}

// ---------------- mean aggregation, bf16 in/out ----------------
// persistent waves, node-strided. One wave per node; quarter q handles rows
// c+q, c+4+q, ...; lane t covers dims t*8..+7 (16B). Predicated 4-deep:
// index loads clamped, row loads exec-masked (zero-filled) -> 4 rows in
// flight even in tails; single waitcnt before the unpack phase.

__global__ __launch_bounds__(256) void k_gather_bf(
    const unsigned short* __restrict__ hin, const int* __restrict__ rowptr,
    const int* __restrict__ col, unsigned short* __restrict__ agg) {
    int lane = threadIdx.x & 63;
    int wid = (blockIdx.x << 2) + (threadIdx.x >> 6);
    int q = lane >> 4, t = lane & 15;
    const int NW = GBLOCKS * 4;
    for (int node = wid; node < N_NODES; node += NW) {
        int start = rowptr[node], end = rowptr[node + 1];
        float acc[8];
#pragma unroll
        for (int j = 0; j < 8; j++) acc[j] = 0.f;

        for (int c = start + q; c < end; c += 16) {
            uint4 v[4];
            int idx[4];
            bool val[4];
#pragma unroll
            for (int k = 0; k < 4; k++) {
                int cc = c + 4 * k;
                val[k] = cc < end;
                idx[k] = col[val[k] ? cc : (end - 1)];
            }
#pragma unroll
            for (int k = 0; k < 4; k++) {
                v[k] = (uint4){0u, 0u, 0u, 0u};
                if (val[k]) v[k] = *(const uint4*)(hin + (size_t)idx[k] * DIM + t * 8);
            }
#pragma unroll
            for (int k = 0; k < 4; k++) {
                const unsigned int* pv = &v[k].x;
#pragma unroll
                for (int j = 0; j < 4; j++) {
                    acc[2 * j + 0] += bf2f((unsigned short)(pv[j] & 0xFFFF));
                    acc[2 * j + 1] += bf2f((unsigned short)(pv[j] >> 16));
                }
            }
        }
#pragma unroll
        for (int j = 0; j < 8; j++) {
            acc[j] += __shfl_xor(acc[j], 16);
            acc[j] += __shfl_xor(acc[j], 32);
        }
        if (q == 0) {
            int deg = end - start;
            float scale = 1.f / (float)(deg > 0 ? deg : 1);
            uint4 o;
            unsigned int* po = &o.x;
#pragma unroll
            for (int j = 0; j < 4; j++)
                po[j] = f2bf(acc[2 * j] * scale) | (f2bf(acc[2 * j + 1] * scale) << 16);
            *(uint4*)(agg + (size_t)node * DIM + t * 8) = o;
        }
    }
}

// ---------------- fused linear via MFMA ----------------
// hout = act([agg | hin] @ [Wl;Wr] + bl).  Block = 256 thr = 4 waves,
// tile 64 rows x 128 cols; wave w owns cols 32w..32w+31 (2 col-tiles),
// all 16 B-frags in registers, A-frags from global with 1-kstep prefetch.

template <bool RELU>
__global__ __launch_bounds__(256) void k_linear_mfma(
    const unsigned short* __restrict__ aggb, const unsigned short* __restrict__ hb,
    const unsigned short* __restrict__ Wt, const float* __restrict__ bl,
    unsigned short* __restrict__ hout) {
    int tid = threadIdx.x;
    int w = tid >> 6, lane = tid & 63;
    int t = lane & 15, q = lane >> 4;
    size_t i0 = (size_t)blockIdx.x * 64;

    bf16x8 bfrag[2][8];
#pragma unroll
    for (int ct2 = 0; ct2 < 2; ct2++)
#pragma unroll
        for (int ks = 0; ks < 8; ks++)
            bfrag[ct2][ks] =
                *(const bf16x8*)(Wt + (size_t)(w * 32 + ct2 * 16 + t) * 256 + ks * 32 + q * 8);

    floatx4 acc[4][2];
#pragma unroll
    for (int rt = 0; rt < 4; rt++)
#pragma unroll
        for (int c = 0; c < 2; c++) acc[rt][c] = (floatx4){0.f, 0.f, 0.f, 0.f};

    bf16x8 a_cur[4];
#pragma unroll
    for (int rt = 0; rt < 4; rt++)
        a_cur[rt] = *(const bf16x8*)(aggb + (i0 + rt * 16 + t) * DIM + q * 8);

#pragma unroll
    for (int ks = 0; ks < 8; ks++) {
        bf16x8 a_nxt[4];
        if (ks < 7) {
            const unsigned short* base = ((ks + 1) < 4) ? aggb : hb;
            int ko = ((ks + 1) & 3) * 32;
#pragma unroll
            for (int rt = 0; rt < 4; rt++)
                a_nxt[rt] = *(const bf16x8*)(base + (i0 + rt * 16 + t) * DIM + ko + q * 8);
        }
#pragma unroll
        for (int rt = 0; rt < 4; rt++) {
            acc[rt][0] = __builtin_amdgcn_mfma_f32_16x16x32_bf16(a_cur[rt], bfrag[0][ks],
                                                                 acc[rt][0], 0, 0, 0);
            acc[rt][1] = __builtin_amdgcn_mfma_f32_16x16x32_bf16(a_cur[rt], bfrag[1][ks],
                                                                 acc[rt][1], 0, 0, 0);
        }
        if (ks < 7) {
#pragma unroll
            for (int rt = 0; rt < 4; rt++) a_cur[rt] = a_nxt[rt];
        }
    }

    float b0 = bl[w * 32 + t];
    float b1 = bl[w * 32 + 16 + t];
#pragma unroll
    for (int rt = 0; rt < 4; rt++) {
#pragma unroll
        for (int r = 0; r < 4; r++) {
            size_t row = i0 + rt * 16 + q * 4 + r;
            float v0 = acc[rt][0][r] + b0;
            float v1 = acc[rt][1][r] + b1;
            if (RELU) {
                v0 = fmaxf(v0, 0.f);
                v1 = fmaxf(v1, 0.f);
            }
            hout[row * DIM + w * 32 + t] = (unsigned short)f2bf(v0);
            hout[row * DIM + w * 32 + 16 + t] = (unsigned short)f2bf(v1);
        }
    }
}

// ---------------- per-graph mean pool (batch sorted), bf16 input ----------------

__global__ void k_pool(const unsigned short* __restrict__ h, const int* __restrict__ batch,
                       float* __restrict__ pooled, float* __restrict__ gcnt) {
    int tid = threadIdx.x;
    int d = tid & 127, half = tid >> 7;
    int n0 = blockIdx.x * 64 + half * 32;
    if (n0 >= N_NODES) return;
    int nend = n0 + 32;
    if (nend > N_NODES) nend = N_NODES;
    float acc = 0.f;
    int cur = batch[n0];
    int run = 0;
    for (int n = n0; n < nend; n++) {
        int g = batch[n];
        if (g != cur) {
            atomicAdd(&pooled[cur * DIM + d], acc);
            if (d == 0) atomicAdd(&gcnt[cur], (float)run);
            acc = 0.f; run = 0; cur = g;
        }
        acc += bf2f(h[(size_t)n * DIM + d]);
        run++;
    }
    atomicAdd(&pooled[cur * DIM + d], acc);
    if (d == 0) atomicAdd(&gcnt[cur], (float)run);
}

__global__ void k_final(const float* __restrict__ pooled, const float* __restrict__ gcnt,
                        const float* __restrict__ Wlin, const float* __restrict__ blin,
                        float* __restrict__ out) {
    int t = threadIdx.x;  // 128 threads
    int g = t >> 1, o = t & 1;
    float sum = 0.f;
#pragma unroll 8
    for (int k = 0; k < DIM; k++) sum += pooled[g * DIM + k] * Wlin[k * 2 + o];
    float c = gcnt[g];
    out[g * 2 + o] = sum / fmaxf(c, 1.f) + blin[o];
}

// ---------------- launch ----------------

static inline size_t align_up(size_t v, size_t a) { return (v + a - 1) & ~(a - 1); }

extern "C" void kernel_launch(void* const* d_in, const int* in_sizes, int n_in,
                              void* d_out, int out_size, void* d_ws, size_t ws_size,
                              hipStream_t stream) {
    const float* x     = (const float*)d_in[0];
    const int*   ei    = (const int*)d_in[1];
    const int*   src   = ei;
    const int*   dst   = ei + N_EDGES;
    const int*   batch = (const int*)d_in[2];
    const float* Wl1 = (const float*)d_in[3];
    const float* bl1 = (const float*)d_in[4];
    const float* Wr1 = (const float*)d_in[5];
    const float* Wl2 = (const float*)d_in[6];
    const float* bl2 = (const float*)d_in[7];
    const float* Wr2 = (const float*)d_in[8];
    const float* Wl3 = (const float*)d_in[9];
    const float* bl3 = (const float*)d_in[10];
    const float* Wr3 = (const float*)d_in[11];
    const float* Wlin = (const float*)d_in[12];
    const float* blin = (const float*)d_in[13];
    float* out = (float*)d_out;

    char* p = (char*)d_ws;
    size_t off = 0;
    auto carve = [&](size_t bytes) -> void* {
        void* r = p + off;
        off = align_up(off + bytes, 256);
        return r;
    };
    int* rowptr = (int*)carve((N_NODES + 1) * sizeof(int));
    int* bcur   = (int*)carve(NBUCKET * sizeof(int));
    int* bbase  = (int*)carve((NBUCKET + 1) * sizeof(int));
    int* col    = (int*)carve((size_t)N_EDGES * sizeof(int));
    unsigned short* bufA = (unsigned short*)carve((size_t)M_PAD * DIM * 2);
    unsigned short* bufB = (unsigned short*)carve((size_t)M_PAD * DIM * 2);
    unsigned short* bufC = (unsigned short*)carve((size_t)M_PAD * DIM * 2);
    unsigned short* agg  = (unsigned short*)carve((size_t)M_PAD * DIM * 2);
    unsigned short* Wt1  = (unsigned short*)carve(256 * 128 * 2);
    unsigned short* Wt2  = (unsigned short*)carve(256 * 128 * 2);
    unsigned short* Wt3  = (unsigned short*)carve(256 * 128 * 2);
    float* pooled = (float*)carve((size_t)NGRAPH * DIM * sizeof(float));
    float* gcnt   = (float*)carve((size_t)NGRAPH * sizeof(float));
    // staging (782*4096*4B = 12.8 MB) aliases bufB: dead after k_bsort, and
    // bufB is first written by layer-1's linear later on the same stream.
    unsigned int* staging = (unsigned int*)bufB;

    // ---- CSR build (chunk-reserved bucket scatter + per-bucket sort) ----
    hipMemsetAsync(bcur, 0, NBUCKET * sizeof(int), stream);
    k_scatter2<<<(N_EDGES + CHUNK - 1) / CHUNK, 1024, 0, stream>>>(src, dst, bcur, staging);
    k_bscan<<<1, 256, 0, stream>>>(bcur, bbase);
    k_bsort<<<NBUCKET, 256, 0, stream>>>(staging, bbase, rowptr, col);

    // ---- conversions (x + all three weight transposes in one dispatch) ----
    k_convert<<<XBLOCKS + 384, 256, 0, stream>>>(x, bufA, Wl1, Wr1, Wt1, Wl2, Wr2, Wt2,
                                                 Wl3, Wr3, Wt3);

    const int GRID_L = M_PAD / 64;         // 1564

    // ---- layer 1 ----
    k_gather_bf<<<GBLOCKS, 256, 0, stream>>>(bufA, rowptr, col, agg);
    k_linear_mfma<true><<<GRID_L, 256, 0, stream>>>(agg, bufA, Wt1, bl1, bufB);
    // ---- layer 2 ----
    k_gather_bf<<<GBLOCKS, 256, 0, stream>>>(bufB, rowptr, col, agg);
    k_linear_mfma<true><<<GRID_L, 256, 0, stream>>>(agg, bufB, Wt2, bl2, bufC);
    // ---- layer 3 ----
    k_gather_bf<<<GBLOCKS, 256, 0, stream>>>(bufC, rowptr, col, agg);
    k_linear_mfma<false><<<GRID_L, 256, 0, stream>>>(agg, bufC, Wt3, bl3, bufA);

    // ---- pool + final ----
    hipMemsetAsync(pooled, 0, NGRAPH * DIM * sizeof(float) + NGRAPH * sizeof(float), stream);
    k_pool<<<(N_NODES + 63) / 64, 256, 0, stream>>>(bufA, batch, pooled, gcnt);
    k_final<<<1, 128, 0, stream>>>(pooled, gcnt, Wlin, blin, out);
}